// Round 14
// baseline (231.704 us; speedup 1.0000x reference)
//
#include <hip/hip_runtime.h>
#include <hip/hip_bf16.h>
#include <stdint.h>

typedef __attribute__((ext_vector_type(8))) short bfrag;
typedef __attribute__((ext_vector_type(4))) short bfrag4;
typedef __attribute__((ext_vector_type(4))) float f32x4;
typedef __attribute__((ext_vector_type(2))) float f32x2;
typedef __attribute__((ext_vector_type(2))) unsigned int u32x2;
typedef __attribute__((ext_vector_type(4))) unsigned int u32x4;

__device__ inline short f2bf(float f) {
  union { float f; uint32_t u; } v; v.f = f;
  uint32_t u = v.u;
  uint32_t r = (u + 0x7fffu + ((u >> 16) & 1u)) >> 16;
  return (short)r;
}
__device__ inline float bf2f(short s) {
  return __builtin_bit_cast(float, (uint32_t)((uint32_t)(uint16_t)s << 16));
}

#if __has_builtin(__builtin_amdgcn_cvt_pk_bf16_f32)
typedef __attribute__((ext_vector_type(2))) __bf16 bf16x2_t;
__device__ inline uint32_t pack_bf16(float a, float b) {
  bf16x2_t r = __builtin_amdgcn_cvt_pk_bf16_f32(a, b);
  return __builtin_bit_cast(uint32_t, r);
}
#else
__device__ inline uint32_t pack_bf16(float a, float b) {
  uint32_t ua = __builtin_bit_cast(uint32_t, a) + 0x8000u;
  uint32_t ub = __builtin_bit_cast(uint32_t, b) + 0x8000u;
  return __builtin_amdgcn_perm(ub, ua, 0x07060302);
}
#endif

// Drain-free workgroup barrier: only my own LDS ops must be complete.
__device__ inline void lds_barrier() {
  asm volatile("s_waitcnt lgkmcnt(0)" ::: "memory");
  __builtin_amdgcn_s_barrier();
  asm volatile("" ::: "memory");
}

// ---------------- prep: ada (blocks 0-15) + weight transposes (16-79) ------
__global__ __launch_bounds__(256) void prep_kernel(
    const float* __restrict__ emb_table, const int* __restrict__ t,
    const float* __restrict__ ada_w, const float* __restrict__ ada_b,
    float* __restrict__ scsh,
    const float* __restrict__ qkv_w, short* __restrict__ qkv_wt,
    const float* __restrict__ proj_w, short* __restrict__ proj_wt) {
  __shared__ float smem[64 * 65];
  const int blk = blockIdx.x;
  const int tid = threadIdx.x;
  if (blk < 16) {
    float* se = smem;
    float* part = smem + 256;
    int b = blk >> 3, ox = blk & 7;
    int tt = t[b];
    float e = emb_table[tt * 256 + tid];
    se[tid] = e / (1.f + __expf(-e));
    __syncthreads();
    int ol = tid & 63, kc = tid >> 6;
    int o = ox * 64 + ol;
    float acc = 0.f;
#pragma unroll 8
    for (int k = kc * 64; k < (kc + 1) * 64; ++k) acc += se[k] * ada_w[k * 512 + o];
    part[tid] = acc;
    __syncthreads();
    if (tid < 64) {
      int oo = ox * 64 + tid;
      scsh[b * 512 + oo] =
          part[tid] + part[64 + tid] + part[128 + tid] + part[192 + tid] + ada_b[oo];
    }
  } else {
    const float* W; short* Wt; int N, lb;
    if (blk < 64) { W = qkv_w; Wt = qkv_wt; N = 768; lb = blk - 16; }
    else          { W = proj_w; Wt = proj_wt; N = 256; lb = blk - 64; }
    float (*tile)[65] = (float(*)[65])smem;
    int k0 = (lb & 3) * 64, n0 = (lb >> 2) * 64;
    int r = tid >> 2, c0 = (tid & 3) * 16;
    const float* src = W + (long)(k0 + r) * N + n0 + c0;
#pragma unroll
    for (int j = 0; j < 16; j += 4) {
      float4 v = *(const float4*)(src + j);
      tile[r][c0 + j] = v.x; tile[r][c0 + j + 1] = v.y;
      tile[r][c0 + j + 2] = v.z; tile[r][c0 + j + 3] = v.w;
    }
    __syncthreads();
    int nl = tid >> 2, kc = (tid & 3) * 16;
    short outv[16];
#pragma unroll
    for (int j = 0; j < 16; ++j) outv[j] = f2bf(tile[kc + j][nl]);
    short* dst = Wt + (long)(n0 + nl) * 256 + k0 + kc;
    *(bfrag*)dst = *(bfrag*)&outv[0];
    *(bfrag*)(dst + 8) = *(bfrag*)&outv[8];
  }
}

// ---------------- LayerNorm + (1+sc)*xn + sh -> bf16, wave-per-row ---------
__global__ __launch_bounds__(256) void ln_kernel(const float* __restrict__ x,
                                                 const float* __restrict__ scsh,
                                                 short* __restrict__ xb) {
  int row = blockIdx.x * 4 + (threadIdx.x >> 6);   // 2048 blocks x 4 rows
  int b = row >> 12;
  int lane = threadIdx.x & 63;
  float4 v = *(const float4*)(x + (long)row * 256 + lane * 4);
  float s = v.x + v.y + v.z + v.w;
  float sq = v.x * v.x + v.y * v.y + v.z * v.z + v.w * v.w;
#pragma unroll
  for (int off = 32; off > 0; off >>= 1) {
    s += __shfl_xor(s, off);
    sq += __shfl_xor(sq, off);
  }
  float mu = s * (1.f / 256.f);
  float var = sq * (1.f / 256.f) - mu * mu;
  float rstd = rsqrtf(var + 1e-5f);
  const float* scp = scsh + b * 512 + lane * 4;
  float4 sc = *(const float4*)scp;
  float4 sh = *(const float4*)(scp + 256);
  float y0 = (v.x - mu) * rstd * (1.f + sc.x) + sh.x;
  float y1 = (v.y - mu) * rstd * (1.f + sc.y) + sh.y;
  float y2 = (v.z - mu) * rstd * (1.f + sc.z) + sh.z;
  float y3 = (v.w - mu) * rstd * (1.f + sc.w) + sh.w;
  u32x2 o; o.x = pack_bf16(y0, y1); o.y = pack_bf16(y2, y3);
  *(u32x2*)&xb[(long)row * 256 + lane * 4] = o;
}

// ---------------- QKV GEMM, 128x64 tile: qkv = xb * qkv_wt^T + bias --------
// cols 0..511 -> qk bf16 (cols<256 scaled by qscale); 512..767 -> vT (transposed).
__global__ __launch_bounds__(256) void gemm_qkv(const short* __restrict__ A,
                                                const short* __restrict__ Bt,
                                                const float* __restrict__ bias,
                                                float qscale,
                                                short* __restrict__ qk,
                                                short* __restrict__ vT) {
  __shared__ short As[128 * 40];
  __shared__ short Bs[64 * 40];
  const int mt = blockIdx.x, nt = blockIdx.y;
  const int tid = threadIdx.x;
  const int w = tid >> 6, lane = tid & 63, l16 = lane & 15, quad = lane >> 4;
  const int ar = tid >> 1, ak = (tid & 1) * 16;
  const int br = tid >> 2, bk = (tid & 3) * 8;
  f32x4 acc[2][4] = {};
  const short* Arow = A + (long)(mt * 128 + ar) * 256 + ak;
  const short* Brow = Bt + (long)(nt * 64 + br) * 256 + bk;
  bfrag a8a = *(const bfrag*)Arow;
  bfrag a8b = *(const bfrag*)(Arow + 8);
  bfrag b8  = *(const bfrag*)Brow;
  for (int kk = 0; kk < 8; ++kk) {
    __syncthreads();
    *(bfrag*)&As[ar * 40 + ak] = a8a;
    *(bfrag*)&As[ar * 40 + ak + 8] = a8b;
    *(bfrag*)&Bs[br * 40 + bk] = b8;
    __syncthreads();
    int kn = (kk < 7) ? (kk + 1) : 7;
    a8a = *(const bfrag*)(Arow + kn * 32);
    a8b = *(const bfrag*)(Arow + kn * 32 + 8);
    b8  = *(const bfrag*)(Brow + kn * 32);
    bfrag a0 = *(const bfrag*)&As[(w * 32 + l16) * 40 + quad * 8];
    bfrag a1 = *(const bfrag*)&As[(w * 32 + 16 + l16) * 40 + quad * 8];
#pragma unroll
    for (int c = 0; c < 4; ++c) {
      bfrag bf = *(const bfrag*)&Bs[(c * 16 + l16) * 40 + quad * 8];
      acc[0][c] = __builtin_amdgcn_mfma_f32_16x16x32_bf16(a0, bf, acc[0][c], 0, 0, 0);
      acc[1][c] = __builtin_amdgcn_mfma_f32_16x16x32_bf16(a1, bf, acc[1][c], 0, 0, 0);
    }
  }
  const int rowb = mt * 128 + w * 32 + quad * 4;
  if (nt < 8) {  // Q,K columns -> qk pitch 512
#pragma unroll
    for (int rg = 0; rg < 2; ++rg) {
      int row0 = rowb + rg * 16;
#pragma unroll
      for (int c = 0; c < 4; ++c) {
        int col = nt * 64 + c * 16 + l16;
        float bv = bias[col];
        float mult = (col < 256) ? qscale : 1.0f;
#pragma unroll
        for (int r = 0; r < 4; ++r)
          qk[(long)(row0 + r) * 512 + col] = f2bf((acc[rg][c][r] + bv) * mult);
      }
    }
  } else {  // V columns -> vT[bh][d][key]
    const int bb = mt >> 5;
#pragma unroll
    for (int rg = 0; rg < 2; ++rg) {
      int keyl = (rowb + rg * 16) & 4095;
#pragma unroll
      for (int c = 0; c < 4; ++c) {
        int col = nt * 64 + c * 16 + l16;
        float bv = bias[col];
        int d = col - 512;
        u32x2 dd;
        dd.x = pack_bf16(acc[rg][c][0] + bv, acc[rg][c][1] + bv);
        dd.y = pack_bf16(acc[rg][c][2] + bv, acc[rg][c][3] + bv);
        *(u32x2*)&vT[((long)(bb * 8 + (d >> 5)) * 32 + (d & 31)) * 4096 + keyl] = dd;
      }
    }
  }
}

// ---------------- flash attention (S^T, O^T PV, KVBLK=128, T14 split) ------
// Grid: 2048 blocks, XCD-aware mapping, 128 q rows/block, keys [ks*1024,+1024).
// T14 async-stage split: per iteration {compute h0 on buf; write tile i+1 ->
// buf^1 (covered by h0); issue prefetch tile i+2; compute h1 on buf;
// lgkm-barrier}. Prefetch-to-use slack = one full iteration (~2x prior);
// the ds_write no longer abuts the barrier. One barrier/iter (same as before).
// Safety: reads of buf^1 all completed before the PREVIOUS barrier, so
// writing buf^1 anywhere in iter i races nothing; the end-of-iter lgkmcnt(0)
// +barrier publishes the writes before iter i+1 reads them.
__global__ __launch_bounds__(256) void attn_kernel(const short* __restrict__ qk,
                                                   const short* __restrict__ vT,
                                                   short* __restrict__ OpB,
                                                   float* __restrict__ lpart) {
  const int bid = blockIdx.x;
  const int c = bid & 7, j = bid >> 3;          // bijective: 2048 = 8 * 256
  const int bh = c * 2 + (j >> 7);
  const int qt = j & 31;
  const int ks = (j >> 5) & 3;
  const int b = bh >> 3, hh = bh & 7;
  const int tid = threadIdx.x;
  const int w = tid >> 6, lane = tid & 63, l16 = lane & 15, quad = lane >> 4;
  const int sig0 = ((l16 >> 2) * 8) + (l16 & 3);   // key-slot permutation

  __shared__ short Ks[2][128 * 36];
  __shared__ short Vt[2][32 * 132];

  const long rowbase = (long)b * 4096;
  const int qrow0 = qt * 128 + w * 32 + l16;
  bfrag qf[2];
#pragma unroll
  for (int g = 0; g < 2; ++g)
    qf[g] = *(const bfrag*)&qk[(rowbase + qrow0 + g * 16) * 512 + hh * 32 + quad * 8];

  f32x4 olo[2] = {}, ohi[2] = {}, osum[2] = {};
  bfrag vones;
#pragma unroll
  for (int jj = 0; jj < 8; ++jj) vones[jj] = (short)0x3F80;   // bf16 1.0

  const int si = tid >> 2, sk = (tid & 3) * 8;
  const int vrow = tid >> 3, vcol = (tid & 7) * 8;
  const short* ksrc = qk + rowbase * 512 + 256 + hh * 32 + (long)si * 512 + sk;
  const short* vsrc = vT + ((long)bh * 32 + vrow) * 4096 + vcol;

  const int kbase = ks * 1024;
  bfrag k8a, k8b, v8a, v8b;

  // half-tile compute (h = 0 or 1 within the 128-key staged tile)
  auto half = [&](const short* KsB, const short* VtB, int h) {
    const int kb0 = h * 64, kb1 = h * 64 + 32;
    bfrag kA0 = *(const bfrag*)&KsB[(kb0 + sig0) * 36 + quad * 8];
    bfrag kA1 = *(const bfrag*)&KsB[(kb0 + sig0 + 4) * 36 + quad * 8];
    bfrag kB0 = *(const bfrag*)&KsB[(kb1 + sig0) * 36 + quad * 8];
    bfrag kB1 = *(const bfrag*)&KsB[(kb1 + sig0 + 4) * 36 + quad * 8];
    bfrag vAlo = *(const bfrag*)&VtB[l16 * 132 + kb0 + quad * 8];
    bfrag vAhi = *(const bfrag*)&VtB[(16 + l16) * 132 + kb0 + quad * 8];
    bfrag vBlo = *(const bfrag*)&VtB[l16 * 132 + kb1 + quad * 8];
    bfrag vBhi = *(const bfrag*)&VtB[(16 + l16) * 132 + kb1 + quad * 8];
    f32x4 z = {0, 0, 0, 0};
    f32x4 sA0[2], sA1[2], sB0[2], sB1[2];
    __builtin_amdgcn_s_setprio(1);
#pragma unroll
    for (int g = 0; g < 2; ++g) {
      sA0[g] = __builtin_amdgcn_mfma_f32_16x16x32_bf16(kA0, qf[g], z, 0, 0, 0);
      sA1[g] = __builtin_amdgcn_mfma_f32_16x16x32_bf16(kA1, qf[g], z, 0, 0, 0);
      sB0[g] = __builtin_amdgcn_mfma_f32_16x16x32_bf16(kB0, qf[g], z, 0, 0, 0);
      sB1[g] = __builtin_amdgcn_mfma_f32_16x16x32_bf16(kB1, qf[g], z, 0, 0, 0);
    }
    __builtin_amdgcn_s_setprio(0);
    bfrag pbA[2], pbB[2];
#pragma unroll
    for (int g = 0; g < 2; ++g) {
      float a0 = __builtin_amdgcn_exp2f(sA0[g][0]);
      float a1 = __builtin_amdgcn_exp2f(sA0[g][1]);
      float a2 = __builtin_amdgcn_exp2f(sA0[g][2]);
      float a3 = __builtin_amdgcn_exp2f(sA0[g][3]);
      float a4 = __builtin_amdgcn_exp2f(sA1[g][0]);
      float a5 = __builtin_amdgcn_exp2f(sA1[g][1]);
      float a6 = __builtin_amdgcn_exp2f(sA1[g][2]);
      float a7 = __builtin_amdgcn_exp2f(sA1[g][3]);
      float b0 = __builtin_amdgcn_exp2f(sB0[g][0]);
      float b1 = __builtin_amdgcn_exp2f(sB0[g][1]);
      float b2 = __builtin_amdgcn_exp2f(sB0[g][2]);
      float b3 = __builtin_amdgcn_exp2f(sB0[g][3]);
      float b4 = __builtin_amdgcn_exp2f(sB1[g][0]);
      float b5 = __builtin_amdgcn_exp2f(sB1[g][1]);
      float b6 = __builtin_amdgcn_exp2f(sB1[g][2]);
      float b7 = __builtin_amdgcn_exp2f(sB1[g][3]);
      u32x4 pka, pkb;
      pka.x = pack_bf16(a0, a1); pka.y = pack_bf16(a2, a3);
      pka.z = pack_bf16(a4, a5); pka.w = pack_bf16(a6, a7);
      pkb.x = pack_bf16(b0, b1); pkb.y = pack_bf16(b2, b3);
      pkb.z = pack_bf16(b4, b5); pkb.w = pack_bf16(b6, b7);
      pbA[g] = __builtin_bit_cast(bfrag, pka);
      pbB[g] = __builtin_bit_cast(bfrag, pkb);
    }
    __builtin_amdgcn_s_setprio(1);
#pragma unroll
    for (int g = 0; g < 2; ++g) {
      olo[g]  = __builtin_amdgcn_mfma_f32_16x16x32_bf16(pbA[g], vAlo, olo[g], 0, 0, 0);
      ohi[g]  = __builtin_amdgcn_mfma_f32_16x16x32_bf16(pbA[g], vAhi, ohi[g], 0, 0, 0);
      osum[g] = __builtin_amdgcn_mfma_f32_16x16x32_bf16(pbA[g], vones, osum[g], 0, 0, 0);
      olo[g]  = __builtin_amdgcn_mfma_f32_16x16x32_bf16(pbB[g], vBlo, olo[g], 0, 0, 0);
      ohi[g]  = __builtin_amdgcn_mfma_f32_16x16x32_bf16(pbB[g], vBhi, ohi[g], 0, 0, 0);
      osum[g] = __builtin_amdgcn_mfma_f32_16x16x32_bf16(pbB[g], vones, osum[g], 0, 0, 0);
    }
    __builtin_amdgcn_s_setprio(0);
  };

  // prologue: stage tile 0 into buf 0; prefetch tile 1 into regs
  k8a = *(const bfrag*)(ksrc + (long)kbase * 512);
  k8b = *(const bfrag*)(ksrc + (long)(kbase + 64) * 512);
  v8a = *(const bfrag*)(vsrc + kbase);
  v8b = *(const bfrag*)(vsrc + kbase + 64);
  *(bfrag*)&Ks[0][si * 36 + sk] = k8a;
  *(bfrag*)&Ks[0][(si + 64) * 36 + sk] = k8b;
  *(bfrag*)&Vt[0][vrow * 132 + vcol] = v8a;
  *(bfrag*)&Vt[0][vrow * 132 + 64 + vcol] = v8b;
  lds_barrier();
  k8a = *(const bfrag*)(ksrc + (long)(kbase + 128) * 512);
  k8b = *(const bfrag*)(ksrc + (long)(kbase + 192) * 512);
  v8a = *(const bfrag*)(vsrc + kbase + 128);
  v8b = *(const bfrag*)(vsrc + kbase + 192);

  for (int i = 0; i < 8; ++i) {
    const int buf = i & 1, nbuf = buf ^ 1;
    // phase A: compute first half of current tile (covers prefetch latency)
    half(Ks[buf], Vt[buf], 0);
    // phase B: write NEXT tile (regs hold tile i+1) into the other buffer
    *(bfrag*)&Ks[nbuf][si * 36 + sk] = k8a;
    *(bfrag*)&Ks[nbuf][(si + 64) * 36 + sk] = k8b;
    *(bfrag*)&Vt[nbuf][vrow * 132 + vcol] = v8a;
    *(bfrag*)&Vt[nbuf][vrow * 132 + 64 + vcol] = v8b;
    // phase C: issue prefetch of tile i+2 (clamped; used mid-iter i+1)
    {
      int nn = (i < 6) ? (i + 2) : 7;
      int kb_n = kbase + nn * 128;
      k8a = *(const bfrag*)(ksrc + (long)kb_n * 512);
      k8b = *(const bfrag*)(ksrc + (long)(kb_n + 64) * 512);
      v8a = *(const bfrag*)(vsrc + kb_n);
      v8b = *(const bfrag*)(vsrc + kb_n + 64);
    }
    // phase D: compute second half of current tile
    half(Ks[buf], Vt[buf], 1);
    // publish nbuf writes for iteration i+1
    lds_barrier();
  }

  // epilogue: O^T layout -> OpB[q][d] u16 stores; lpart from osum (f32x4)
  uint16_t* Ob = (uint16_t*)OpB;
  const long obase = ((long)ks * 16 + bh) * 4096;
  const int qgb = qt * 128 + w * 32;
#pragma unroll
  for (int g = 0; g < 2; ++g) {
    if (l16 == 0)
      *(f32x4*)&lpart[obase + qgb + g * 16 + quad * 4] = osum[g];
#pragma unroll
    for (int r = 0; r < 4; ++r) {
      int q = qgb + g * 16 + quad * 4 + r;
      uint32_t pk = pack_bf16(olo[g][r], ohi[g][r]);
      Ob[(obase + q) * 32 + l16] = (uint16_t)pk;
      Ob[(obase + q) * 32 + l16 + 16] = (uint16_t)(pk >> 16);
    }
  }
}

// ---------------- proj GEMM with fused key-split reduce --------------------
// A[row][d] = (sum_ks OpB) / (sum_ks lpart), computed during A-staging.
// Head hh == kk (K-step index): A cols kk*32..+31 come from OpB head kk.
// C = A[8192,256] * proj_wt^T + proj_b -> fp32 out. Grid (64,4), 128x64 tile.
__global__ __launch_bounds__(256) void proj_kernel(const short* __restrict__ OpB,
                                                   const float* __restrict__ lpart,
                                                   const short* __restrict__ Bt,
                                                   const float* __restrict__ bias,
                                                   float* __restrict__ out) {
  __shared__ short As[128 * 40];
  __shared__ short Bs[64 * 40];
  const int mt = blockIdx.x, nt = blockIdx.y;
  const int tid = threadIdx.x;
  const int w = tid >> 6, lane = tid & 63, l16 = lane & 15, quad = lane >> 4;
  const int ar = tid >> 1, ak = (tid & 1) * 16;   // A: 128 rows x 32 cols/iter
  const int br = tid >> 2, bk = (tid & 3) * 8;
  f32x4 acc[2][4] = {};

  const int row = mt * 128 + ar;
  const int q = row & 4095, bq = row >> 12;
  const short* Brow = Bt + (long)(nt * 64 + br) * 256 + bk;

  // prefetch kk=0 (head hh = kk; OpB row index = (ks*16 + bq*8 + kk)*4096 + q)
  long lb0 = (long)(bq * 8) * 4096 + q;
  bfrag pa[4][2];            // [ks][half]: 16 shorts per ks = d ak..ak+15
  f32x4 pl;
#pragma unroll
  for (int ks = 0; ks < 4; ++ks) {
    long base = (lb0 + (long)ks * 16 * 4096) * 32 + ak;
    pa[ks][0] = *(const bfrag*)&OpB[base];
    pa[ks][1] = *(const bfrag*)&OpB[base + 8];
    pl[ks] = lpart[lb0 + (long)ks * 16 * 4096];
  }
  bfrag b8 = *(const bfrag*)Brow;

  for (int kk = 0; kk < 8; ++kk) {
    // combine partials -> bf16 A fragment
    float linv = 1.f / (pl[0] + pl[1] + pl[2] + pl[3]);
    short av[16];
#pragma unroll
    for (int h = 0; h < 2; ++h) {
#pragma unroll
      for (int j = 0; j < 8; j += 2) {
        float v0 = (bf2f(pa[0][h][j]) + bf2f(pa[1][h][j]) +
                    bf2f(pa[2][h][j]) + bf2f(pa[3][h][j])) * linv;
        float v1 = (bf2f(pa[0][h][j+1]) + bf2f(pa[1][h][j+1]) +
                    bf2f(pa[2][h][j+1]) + bf2f(pa[3][h][j+1])) * linv;
        *(uint32_t*)&av[h * 8 + j] = pack_bf16(v0, v1);
      }
    }
    __syncthreads();
    *(bfrag*)&As[ar * 40 + ak] = *(bfrag*)&av[0];
    *(bfrag*)&As[ar * 40 + ak + 8] = *(bfrag*)&av[8];
    *(bfrag*)&Bs[br * 40 + bk] = b8;
    __syncthreads();
    // prefetch next kk
    int kn = (kk < 7) ? (kk + 1) : 7;
    long lbn = (long)(bq * 8 + kn) * 4096 + q;
#pragma unroll
    for (int ks = 0; ks < 4; ++ks) {
      long base = (lbn + (long)ks * 16 * 4096) * 32 + ak;
      pa[ks][0] = *(const bfrag*)&OpB[base];
      pa[ks][1] = *(const bfrag*)&OpB[base + 8];
      pl[ks] = lpart[lbn + (long)ks * 16 * 4096];
    }
    b8 = *(const bfrag*)(Brow + kn * 32);

    bfrag a0 = *(const bfrag*)&As[(w * 32 + l16) * 40 + quad * 8];
    bfrag a1 = *(const bfrag*)&As[(w * 32 + 16 + l16) * 40 + quad * 8];
#pragma unroll
    for (int c = 0; c < 4; ++c) {
      bfrag bf = *(const bfrag*)&Bs[(c * 16 + l16) * 40 + quad * 8];
      acc[0][c] = __builtin_amdgcn_mfma_f32_16x16x32_bf16(a0, bf, acc[0][c], 0, 0, 0);
      acc[1][c] = __builtin_amdgcn_mfma_f32_16x16x32_bf16(a1, bf, acc[1][c], 0, 0, 0);
    }
  }
  const int rowb = mt * 128 + w * 32 + quad * 4;
#pragma unroll
  for (int rg = 0; rg < 2; ++rg) {
    int row0 = rowb + rg * 16;
#pragma unroll
    for (int c = 0; c < 4; ++c) {
      int col = nt * 64 + c * 16 + l16;
      float bv = bias[col];
#pragma unroll
      for (int r = 0; r < 4; ++r)
        out[(long)(row0 + r) * 256 + col] = acc[rg][c][r] + bv;
    }
  }
}

extern "C" void kernel_launch(void* const* d_in, const int* in_sizes, int n_in,
                              void* d_out, int out_size, void* d_ws, size_t ws_size,
                              hipStream_t stream) {
  const float* x      = (const float*)d_in[0];
  // d_in[1] = cond (unused by reference)
  const int*   t      = (const int*)d_in[2];
  const float* emb    = (const float*)d_in[3];
  const float* ada_w  = (const float*)d_in[4];
  const float* ada_b  = (const float*)d_in[5];
  const float* qkv_w  = (const float*)d_in[6];
  const float* qkv_b  = (const float*)d_in[7];
  const float* proj_w = (const float*)d_in[8];
  const float* proj_b = (const float*)d_in[9];

  char* ws = (char*)d_ws;
  float* scsh     = (float*)(ws);                  //   4 KB  [2][512]
  short* qkv_wt   = (short*)(ws + 4096);           // 384 KB  [768][256]
  short* proj_wt  = (short*)(ws + 397312);         // 128 KB  [256][256]
  short* xb       = (short*)(ws + 528384);         //   4 MB  [8192][256]
  short* qk_out   = (short*)(ws + 4722688);        //   8 MB  [8192][512]
  short* vT       = (short*)(ws + 13111296);       //   4 MB  [16][32][4096]
  short* OpB      = (short*)(ws + 21499904);       //  16 MB  [4][16][4096][32] bf16
  float* lpart    = (float*)(ws + 38277120);       //   1 MB  [4][16][4096]

  const float QS = 0.17677669529663687f * 1.4426950408889634f;  // scale*log2e

  prep_kernel<<<80, 256, 0, stream>>>(emb, t, ada_w, ada_b, scsh,
                                      qkv_w, qkv_wt, proj_w, proj_wt);
  ln_kernel<<<2048, 256, 0, stream>>>(x, scsh, xb);
  gemm_qkv<<<dim3(64, 12), 256, 0, stream>>>(xb, qkv_wt, qkv_b, QS, qk_out, vT);
  attn_kernel<<<2048, 256, 0, stream>>>(qk_out, vT, OpB, lpart);
  proj_kernel<<<dim3(64, 4), 256, 0, stream>>>(OpB, lpart, proj_wt, proj_b,
                                               (float*)d_out);
}

// Round 15
// 162.574 us; speedup vs baseline: 1.4252x; 1.4252x over previous
//
#include <hip/hip_runtime.h>
#include <hip/hip_bf16.h>
#include <stdint.h>

typedef __attribute__((ext_vector_type(8))) short bfrag;
typedef __attribute__((ext_vector_type(4))) short bfrag4;
typedef __attribute__((ext_vector_type(4))) float f32x4;
typedef __attribute__((ext_vector_type(2))) float f32x2;
typedef __attribute__((ext_vector_type(2))) unsigned int u32x2;
typedef __attribute__((ext_vector_type(4))) unsigned int u32x4;

__device__ inline short f2bf(float f) {
  union { float f; uint32_t u; } v; v.f = f;
  uint32_t u = v.u;
  uint32_t r = (u + 0x7fffu + ((u >> 16) & 1u)) >> 16;
  return (short)r;
}
__device__ inline float bf2f(short s) {
  return __builtin_bit_cast(float, (uint32_t)((uint32_t)(uint16_t)s << 16));
}

#if __has_builtin(__builtin_amdgcn_cvt_pk_bf16_f32)
typedef __attribute__((ext_vector_type(2))) __bf16 bf16x2_t;
__device__ inline uint32_t pack_bf16(float a, float b) {
  bf16x2_t r = __builtin_amdgcn_cvt_pk_bf16_f32(a, b);
  return __builtin_bit_cast(uint32_t, r);
}
#else
__device__ inline uint32_t pack_bf16(float a, float b) {
  uint32_t ua = __builtin_bit_cast(uint32_t, a) + 0x8000u;
  uint32_t ub = __builtin_bit_cast(uint32_t, b) + 0x8000u;
  return __builtin_amdgcn_perm(ub, ua, 0x07060302);
}
#endif

// Drain-free workgroup barrier: only my own LDS ops must be complete.
__device__ inline void lds_barrier() {
  asm volatile("s_waitcnt lgkmcnt(0)" ::: "memory");
  __builtin_amdgcn_s_barrier();
  asm volatile("" ::: "memory");
}

// ---------------- prep: ada (blocks 0-15) + weight transposes (16-79) ------
__global__ __launch_bounds__(256) void prep_kernel(
    const float* __restrict__ emb_table, const int* __restrict__ t,
    const float* __restrict__ ada_w, const float* __restrict__ ada_b,
    float* __restrict__ scsh,
    const float* __restrict__ qkv_w, short* __restrict__ qkv_wt,
    const float* __restrict__ proj_w, short* __restrict__ proj_wt) {
  __shared__ float smem[64 * 65];
  const int blk = blockIdx.x;
  const int tid = threadIdx.x;
  if (blk < 16) {
    float* se = smem;
    float* part = smem + 256;
    int b = blk >> 3, ox = blk & 7;
    int tt = t[b];
    float e = emb_table[tt * 256 + tid];
    se[tid] = e / (1.f + __expf(-e));
    __syncthreads();
    int ol = tid & 63, kc = tid >> 6;
    int o = ox * 64 + ol;
    float acc = 0.f;
#pragma unroll 8
    for (int k = kc * 64; k < (kc + 1) * 64; ++k) acc += se[k] * ada_w[k * 512 + o];
    part[tid] = acc;
    __syncthreads();
    if (tid < 64) {
      int oo = ox * 64 + tid;
      scsh[b * 512 + oo] =
          part[tid] + part[64 + tid] + part[128 + tid] + part[192 + tid] + ada_b[oo];
    }
  } else {
    const float* W; short* Wt; int N, lb;
    if (blk < 64) { W = qkv_w; Wt = qkv_wt; N = 768; lb = blk - 16; }
    else          { W = proj_w; Wt = proj_wt; N = 256; lb = blk - 64; }
    float (*tile)[65] = (float(*)[65])smem;
    int k0 = (lb & 3) * 64, n0 = (lb >> 2) * 64;
    int r = tid >> 2, c0 = (tid & 3) * 16;
    const float* src = W + (long)(k0 + r) * N + n0 + c0;
#pragma unroll
    for (int j = 0; j < 16; j += 4) {
      float4 v = *(const float4*)(src + j);
      tile[r][c0 + j] = v.x; tile[r][c0 + j + 1] = v.y;
      tile[r][c0 + j + 2] = v.z; tile[r][c0 + j + 3] = v.w;
    }
    __syncthreads();
    int nl = tid >> 2, kc = (tid & 3) * 16;
    short outv[16];
#pragma unroll
    for (int j = 0; j < 16; ++j) outv[j] = f2bf(tile[kc + j][nl]);
    short* dst = Wt + (long)(n0 + nl) * 256 + k0 + kc;
    *(bfrag*)dst = *(bfrag*)&outv[0];
    *(bfrag*)(dst + 8) = *(bfrag*)&outv[8];
  }
}

// ---------------- LayerNorm + (1+sc)*xn + sh -> bf16, wave-per-row ---------
__global__ __launch_bounds__(256) void ln_kernel(const float* __restrict__ x,
                                                 const float* __restrict__ scsh,
                                                 short* __restrict__ xb) {
  int row = blockIdx.x * 4 + (threadIdx.x >> 6);   // 2048 blocks x 4 rows
  int b = row >> 12;
  int lane = threadIdx.x & 63;
  float4 v = *(const float4*)(x + (long)row * 256 + lane * 4);
  float s = v.x + v.y + v.z + v.w;
  float sq = v.x * v.x + v.y * v.y + v.z * v.z + v.w * v.w;
#pragma unroll
  for (int off = 32; off > 0; off >>= 1) {
    s += __shfl_xor(s, off);
    sq += __shfl_xor(sq, off);
  }
  float mu = s * (1.f / 256.f);
  float var = sq * (1.f / 256.f) - mu * mu;
  float rstd = rsqrtf(var + 1e-5f);
  const float* scp = scsh + b * 512 + lane * 4;
  float4 sc = *(const float4*)scp;
  float4 sh = *(const float4*)(scp + 256);
  float y0 = (v.x - mu) * rstd * (1.f + sc.x) + sh.x;
  float y1 = (v.y - mu) * rstd * (1.f + sc.y) + sh.y;
  float y2 = (v.z - mu) * rstd * (1.f + sc.z) + sh.z;
  float y3 = (v.w - mu) * rstd * (1.f + sc.w) + sh.w;
  u32x2 o; o.x = pack_bf16(y0, y1); o.y = pack_bf16(y2, y3);
  *(u32x2*)&xb[(long)row * 256 + lane * 4] = o;
}

// ---------------- QKV GEMM, 128x64 tile: qkv = xb * qkv_wt^T + bias --------
// cols 0..511 -> qk bf16 (cols<256 scaled by qscale); 512..767 -> vT (transposed).
__global__ __launch_bounds__(256) void gemm_qkv(const short* __restrict__ A,
                                                const short* __restrict__ Bt,
                                                const float* __restrict__ bias,
                                                float qscale,
                                                short* __restrict__ qk,
                                                short* __restrict__ vT) {
  __shared__ short As[128 * 40];
  __shared__ short Bs[64 * 40];
  const int mt = blockIdx.x, nt = blockIdx.y;
  const int tid = threadIdx.x;
  const int w = tid >> 6, lane = tid & 63, l16 = lane & 15, quad = lane >> 4;
  const int ar = tid >> 1, ak = (tid & 1) * 16;
  const int br = tid >> 2, bk = (tid & 3) * 8;
  f32x4 acc[2][4] = {};
  const short* Arow = A + (long)(mt * 128 + ar) * 256 + ak;
  const short* Brow = Bt + (long)(nt * 64 + br) * 256 + bk;
  bfrag a8a = *(const bfrag*)Arow;
  bfrag a8b = *(const bfrag*)(Arow + 8);
  bfrag b8  = *(const bfrag*)Brow;
  for (int kk = 0; kk < 8; ++kk) {
    __syncthreads();
    *(bfrag*)&As[ar * 40 + ak] = a8a;
    *(bfrag*)&As[ar * 40 + ak + 8] = a8b;
    *(bfrag*)&Bs[br * 40 + bk] = b8;
    __syncthreads();
    int kn = (kk < 7) ? (kk + 1) : 7;
    a8a = *(const bfrag*)(Arow + kn * 32);
    a8b = *(const bfrag*)(Arow + kn * 32 + 8);
    b8  = *(const bfrag*)(Brow + kn * 32);
    bfrag a0 = *(const bfrag*)&As[(w * 32 + l16) * 40 + quad * 8];
    bfrag a1 = *(const bfrag*)&As[(w * 32 + 16 + l16) * 40 + quad * 8];
#pragma unroll
    for (int c = 0; c < 4; ++c) {
      bfrag bf = *(const bfrag*)&Bs[(c * 16 + l16) * 40 + quad * 8];
      acc[0][c] = __builtin_amdgcn_mfma_f32_16x16x32_bf16(a0, bf, acc[0][c], 0, 0, 0);
      acc[1][c] = __builtin_amdgcn_mfma_f32_16x16x32_bf16(a1, bf, acc[1][c], 0, 0, 0);
    }
  }
  const int rowb = mt * 128 + w * 32 + quad * 4;
  if (nt < 8) {  // Q,K columns -> qk pitch 512
#pragma unroll
    for (int rg = 0; rg < 2; ++rg) {
      int row0 = rowb + rg * 16;
#pragma unroll
      for (int c = 0; c < 4; ++c) {
        int col = nt * 64 + c * 16 + l16;
        float bv = bias[col];
        float mult = (col < 256) ? qscale : 1.0f;
#pragma unroll
        for (int r = 0; r < 4; ++r)
          qk[(long)(row0 + r) * 512 + col] = f2bf((acc[rg][c][r] + bv) * mult);
      }
    }
  } else {  // V columns -> vT[bh][d][key]
    const int bb = mt >> 5;
#pragma unroll
    for (int rg = 0; rg < 2; ++rg) {
      int keyl = (rowb + rg * 16) & 4095;
#pragma unroll
      for (int c = 0; c < 4; ++c) {
        int col = nt * 64 + c * 16 + l16;
        float bv = bias[col];
        int d = col - 512;
        u32x2 dd;
        dd.x = pack_bf16(acc[rg][c][0] + bv, acc[rg][c][1] + bv);
        dd.y = pack_bf16(acc[rg][c][2] + bv, acc[rg][c][3] + bv);
        *(u32x2*)&vT[((long)(bb * 8 + (d >> 5)) * 32 + (d & 31)) * 4096 + keyl] = dd;
      }
    }
  }
}

// ---------------- flash attention (S^T, O^T PV, KVBLK=128, phase-split) ----
// Grid: 2048 blocks, XCD-aware mapping, 128 q rows/block, keys [ks*1024,+1024).
// Per 64-key half: ALL 8 ds_read_b128 issued together (latencies overlap) ->
// all 8 QK MFMA -> all 32 exp2 + 16 cvt_pk -> all 12 PV MFMA. lsum computed
// on the MFMA pipe via a constant all-ones B operand (row-sums land in the
// O-accumulator layout), deleting the per-tile VALU adds + epilogue shuffles.
__global__ __launch_bounds__(256) void attn_kernel(const short* __restrict__ qk,
                                                   const short* __restrict__ vT,
                                                   short* __restrict__ OpB,
                                                   float* __restrict__ lpart) {
  const int bid = blockIdx.x;
  const int c = bid & 7, j = bid >> 3;          // bijective: 2048 = 8 * 256
  const int bh = c * 2 + (j >> 7);
  const int qt = j & 31;
  const int ks = (j >> 5) & 3;
  const int b = bh >> 3, hh = bh & 7;
  const int tid = threadIdx.x;
  const int w = tid >> 6, lane = tid & 63, l16 = lane & 15, quad = lane >> 4;
  const int sig0 = ((l16 >> 2) * 8) + (l16 & 3);   // key-slot permutation

  __shared__ short Ks[2][128 * 36];
  __shared__ short Vt[2][32 * 132];

  const long rowbase = (long)b * 4096;
  const int qrow0 = qt * 128 + w * 32 + l16;
  bfrag qf[2];
#pragma unroll
  for (int g = 0; g < 2; ++g)
    qf[g] = *(const bfrag*)&qk[(rowbase + qrow0 + g * 16) * 512 + hh * 32 + quad * 8];

  f32x4 olo[2] = {}, ohi[2] = {}, osum[2] = {};
  bfrag vones;
#pragma unroll
  for (int jj = 0; jj < 8; ++jj) vones[jj] = (short)0x3F80;   // bf16 1.0

  const int si = tid >> 2, sk = (tid & 3) * 8;
  const int vrow = tid >> 3, vcol = (tid & 7) * 8;
  const short* ksrc = qk + rowbase * 512 + 256 + hh * 32 + (long)si * 512 + sk;
  const short* vsrc = vT + ((long)bh * 32 + vrow) * 4096 + vcol;

  const int kbase = ks * 1024;
  bfrag k8a = *(const bfrag*)(ksrc + (long)kbase * 512);
  bfrag k8b = *(const bfrag*)(ksrc + (long)(kbase + 64) * 512);
  bfrag v8a = *(const bfrag*)(vsrc + kbase);
  bfrag v8b = *(const bfrag*)(vsrc + kbase + 64);

  int buf = 0;
  for (int i = 0; i < 8; ++i) {
    *(bfrag*)&Ks[buf][si * 36 + sk] = k8a;
    *(bfrag*)&Ks[buf][(si + 64) * 36 + sk] = k8b;
    *(bfrag*)&Vt[buf][vrow * 132 + vcol] = v8a;
    *(bfrag*)&Vt[buf][vrow * 132 + 64 + vcol] = v8b;
    lds_barrier();                 // drain-free: prefetch stays in flight
    int nn = (i < 7) ? (i + 1) : 7;
    int kb_n = kbase + nn * 128;
    k8a = *(const bfrag*)(ksrc + (long)kb_n * 512);
    k8b = *(const bfrag*)(ksrc + (long)(kb_n + 64) * 512);
    v8a = *(const bfrag*)(vsrc + kb_n);
    v8b = *(const bfrag*)(vsrc + kb_n + 64);

#pragma unroll
    for (int h = 0; h < 2; ++h) {            // two 64-key halves
      const int kb0 = h * 64, kb1 = h * 64 + 32;
      // phase 1: all LDS reads (8x ds_read_b128, latencies overlap)
      bfrag kA0 = *(const bfrag*)&Ks[buf][(kb0 + sig0) * 36 + quad * 8];
      bfrag kA1 = *(const bfrag*)&Ks[buf][(kb0 + sig0 + 4) * 36 + quad * 8];
      bfrag kB0 = *(const bfrag*)&Ks[buf][(kb1 + sig0) * 36 + quad * 8];
      bfrag kB1 = *(const bfrag*)&Ks[buf][(kb1 + sig0 + 4) * 36 + quad * 8];
      bfrag vAlo = *(const bfrag*)&Vt[buf][l16 * 132 + kb0 + quad * 8];
      bfrag vAhi = *(const bfrag*)&Vt[buf][(16 + l16) * 132 + kb0 + quad * 8];
      bfrag vBlo = *(const bfrag*)&Vt[buf][l16 * 132 + kb1 + quad * 8];
      bfrag vBhi = *(const bfrag*)&Vt[buf][(16 + l16) * 132 + kb1 + quad * 8];
      f32x4 z = {0, 0, 0, 0};
      f32x4 sA0[2], sA1[2], sB0[2], sB1[2];
      // phase 2: all QK MFMA
      __builtin_amdgcn_s_setprio(1);
#pragma unroll
      for (int g = 0; g < 2; ++g) {
        sA0[g] = __builtin_amdgcn_mfma_f32_16x16x32_bf16(kA0, qf[g], z, 0, 0, 0);
        sA1[g] = __builtin_amdgcn_mfma_f32_16x16x32_bf16(kA1, qf[g], z, 0, 0, 0);
        sB0[g] = __builtin_amdgcn_mfma_f32_16x16x32_bf16(kB0, qf[g], z, 0, 0, 0);
        sB1[g] = __builtin_amdgcn_mfma_f32_16x16x32_bf16(kB1, qf[g], z, 0, 0, 0);
      }
      __builtin_amdgcn_s_setprio(0);
      // phase 3: all softmax VALU (32 exp2, 16 cvt_pk)
      bfrag pbA[2], pbB[2];
#pragma unroll
      for (int g = 0; g < 2; ++g) {
        float a0 = __builtin_amdgcn_exp2f(sA0[g][0]);
        float a1 = __builtin_amdgcn_exp2f(sA0[g][1]);
        float a2 = __builtin_amdgcn_exp2f(sA0[g][2]);
        float a3 = __builtin_amdgcn_exp2f(sA0[g][3]);
        float a4 = __builtin_amdgcn_exp2f(sA1[g][0]);
        float a5 = __builtin_amdgcn_exp2f(sA1[g][1]);
        float a6 = __builtin_amdgcn_exp2f(sA1[g][2]);
        float a7 = __builtin_amdgcn_exp2f(sA1[g][3]);
        float b0 = __builtin_amdgcn_exp2f(sB0[g][0]);
        float b1 = __builtin_amdgcn_exp2f(sB0[g][1]);
        float b2 = __builtin_amdgcn_exp2f(sB0[g][2]);
        float b3 = __builtin_amdgcn_exp2f(sB0[g][3]);
        float b4 = __builtin_amdgcn_exp2f(sB1[g][0]);
        float b5 = __builtin_amdgcn_exp2f(sB1[g][1]);
        float b6 = __builtin_amdgcn_exp2f(sB1[g][2]);
        float b7 = __builtin_amdgcn_exp2f(sB1[g][3]);
        u32x4 pka, pkb;
        pka.x = pack_bf16(a0, a1); pka.y = pack_bf16(a2, a3);
        pka.z = pack_bf16(a4, a5); pka.w = pack_bf16(a6, a7);
        pkb.x = pack_bf16(b0, b1); pkb.y = pack_bf16(b2, b3);
        pkb.z = pack_bf16(b4, b5); pkb.w = pack_bf16(b6, b7);
        pbA[g] = __builtin_bit_cast(bfrag, pka);
        pbB[g] = __builtin_bit_cast(bfrag, pkb);
      }
      // phase 4: all PV MFMA (+ row-sum via all-ones operand)
      __builtin_amdgcn_s_setprio(1);
#pragma unroll
      for (int g = 0; g < 2; ++g) {
        olo[g]  = __builtin_amdgcn_mfma_f32_16x16x32_bf16(pbA[g], vAlo, olo[g], 0, 0, 0);
        ohi[g]  = __builtin_amdgcn_mfma_f32_16x16x32_bf16(pbA[g], vAhi, ohi[g], 0, 0, 0);
        osum[g] = __builtin_amdgcn_mfma_f32_16x16x32_bf16(pbA[g], vones, osum[g], 0, 0, 0);
        olo[g]  = __builtin_amdgcn_mfma_f32_16x16x32_bf16(pbB[g], vBlo, olo[g], 0, 0, 0);
        ohi[g]  = __builtin_amdgcn_mfma_f32_16x16x32_bf16(pbB[g], vBhi, ohi[g], 0, 0, 0);
        osum[g] = __builtin_amdgcn_mfma_f32_16x16x32_bf16(pbB[g], vones, osum[g], 0, 0, 0);
      }
      __builtin_amdgcn_s_setprio(0);
    }
    buf ^= 1;
  }
  // epilogue: O^T layout -> OpB[q][d] u16 stores; lpart from osum (f32x4)
  uint16_t* Ob = (uint16_t*)OpB;
  const long obase = ((long)ks * 16 + bh) * 4096;
  const int qgb = qt * 128 + w * 32;
#pragma unroll
  for (int g = 0; g < 2; ++g) {
    if (l16 == 0)
      *(f32x4*)&lpart[obase + qgb + g * 16 + quad * 4] = osum[g];
#pragma unroll
    for (int r = 0; r < 4; ++r) {
      int q = qgb + g * 16 + quad * 4 + r;
      uint32_t pk = pack_bf16(olo[g][r], ohi[g][r]);
      Ob[(obase + q) * 32 + l16] = (uint16_t)pk;
      Ob[(obase + q) * 32 + l16 + 16] = (uint16_t)(pk >> 16);
    }
  }
}

// ---------------- proj GEMM with fused key-split reduce --------------------
// A[row][d] = (sum_ks OpB) / (sum_ks lpart), computed during A-staging.
// Head hh == kk (K-step index): A cols kk*32..+31 come from OpB head kk.
// C = A[8192,256] * proj_wt^T + proj_b -> fp32 out. Grid (64,4), 128x64 tile.
__global__ __launch_bounds__(256) void proj_kernel(const short* __restrict__ OpB,
                                                   const float* __restrict__ lpart,
                                                   const short* __restrict__ Bt,
                                                   const float* __restrict__ bias,
                                                   float* __restrict__ out) {
  __shared__ short As[128 * 40];
  __shared__ short Bs[64 * 40];
  const int mt = blockIdx.x, nt = blockIdx.y;
  const int tid = threadIdx.x;
  const int w = tid >> 6, lane = tid & 63, l16 = lane & 15, quad = lane >> 4;
  const int ar = tid >> 1, ak = (tid & 1) * 16;   // A: 128 rows x 32 cols/iter
  const int br = tid >> 2, bk = (tid & 3) * 8;
  f32x4 acc[2][4] = {};

  const int row = mt * 128 + ar;
  const int q = row & 4095, bq = row >> 12;
  const short* Brow = Bt + (long)(nt * 64 + br) * 256 + bk;

  // prefetch kk=0 (head hh = kk; OpB row index = (ks*16 + bq*8 + kk)*4096 + q)
  long lb0 = (long)(bq * 8) * 4096 + q;
  bfrag pa[4][2];            // [ks][half]: 16 shorts per ks = d ak..ak+15
  f32x4 pl;
#pragma unroll
  for (int ks = 0; ks < 4; ++ks) {
    long base = (lb0 + (long)ks * 16 * 4096) * 32 + ak;
    pa[ks][0] = *(const bfrag*)&OpB[base];
    pa[ks][1] = *(const bfrag*)&OpB[base + 8];
    pl[ks] = lpart[lb0 + (long)ks * 16 * 4096];
  }
  bfrag b8 = *(const bfrag*)Brow;

  for (int kk = 0; kk < 8; ++kk) {
    // combine partials -> bf16 A fragment
    float linv = 1.f / (pl[0] + pl[1] + pl[2] + pl[3]);
    short av[16];
#pragma unroll
    for (int h = 0; h < 2; ++h) {
#pragma unroll
      for (int j = 0; j < 8; j += 2) {
        float v0 = (bf2f(pa[0][h][j]) + bf2f(pa[1][h][j]) +
                    bf2f(pa[2][h][j]) + bf2f(pa[3][h][j])) * linv;
        float v1 = (bf2f(pa[0][h][j+1]) + bf2f(pa[1][h][j+1]) +
                    bf2f(pa[2][h][j+1]) + bf2f(pa[3][h][j+1])) * linv;
        *(uint32_t*)&av[h * 8 + j] = pack_bf16(v0, v1);
      }
    }
    __syncthreads();
    *(bfrag*)&As[ar * 40 + ak] = *(bfrag*)&av[0];
    *(bfrag*)&As[ar * 40 + ak + 8] = *(bfrag*)&av[8];
    *(bfrag*)&Bs[br * 40 + bk] = b8;
    __syncthreads();
    // prefetch next kk
    int kn = (kk < 7) ? (kk + 1) : 7;
    long lbn = (long)(bq * 8 + kn) * 4096 + q;
#pragma unroll
    for (int ks = 0; ks < 4; ++ks) {
      long base = (lbn + (long)ks * 16 * 4096) * 32 + ak;
      pa[ks][0] = *(const bfrag*)&OpB[base];
      pa[ks][1] = *(const bfrag*)&OpB[base + 8];
      pl[ks] = lpart[lbn + (long)ks * 16 * 4096];
    }
    b8 = *(const bfrag*)(Brow + kn * 32);

    bfrag a0 = *(const bfrag*)&As[(w * 32 + l16) * 40 + quad * 8];
    bfrag a1 = *(const bfrag*)&As[(w * 32 + 16 + l16) * 40 + quad * 8];
#pragma unroll
    for (int c = 0; c < 4; ++c) {
      bfrag bf = *(const bfrag*)&Bs[(c * 16 + l16) * 40 + quad * 8];
      acc[0][c] = __builtin_amdgcn_mfma_f32_16x16x32_bf16(a0, bf, acc[0][c], 0, 0, 0);
      acc[1][c] = __builtin_amdgcn_mfma_f32_16x16x32_bf16(a1, bf, acc[1][c], 0, 0, 0);
    }
  }
  const int rowb = mt * 128 + w * 32 + quad * 4;
#pragma unroll
  for (int rg = 0; rg < 2; ++rg) {
    int row0 = rowb + rg * 16;
#pragma unroll
    for (int c = 0; c < 4; ++c) {
      int col = nt * 64 + c * 16 + l16;
      float bv = bias[col];
#pragma unroll
      for (int r = 0; r < 4; ++r)
        out[(long)(row0 + r) * 256 + col] = acc[rg][c][r] + bv;
    }
  }
}

extern "C" void kernel_launch(void* const* d_in, const int* in_sizes, int n_in,
                              void* d_out, int out_size, void* d_ws, size_t ws_size,
                              hipStream_t stream) {
  const float* x      = (const float*)d_in[0];
  // d_in[1] = cond (unused by reference)
  const int*   t      = (const int*)d_in[2];
  const float* emb    = (const float*)d_in[3];
  const float* ada_w  = (const float*)d_in[4];
  const float* ada_b  = (const float*)d_in[5];
  const float* qkv_w  = (const float*)d_in[6];
  const float* qkv_b  = (const float*)d_in[7];
  const float* proj_w = (const float*)d_in[8];
  const float* proj_b = (const float*)d_in[9];

  char* ws = (char*)d_ws;
  float* scsh     = (float*)(ws);                  //   4 KB  [2][512]
  short* qkv_wt   = (short*)(ws + 4096);           // 384 KB  [768][256]
  short* proj_wt  = (short*)(ws + 397312);         // 128 KB  [256][256]
  short* xb       = (short*)(ws + 528384);         //   4 MB  [8192][256]
  short* qk_out   = (short*)(ws + 4722688);        //   8 MB  [8192][512]
  short* vT       = (short*)(ws + 13111296);       //   4 MB  [16][32][4096]
  short* OpB      = (short*)(ws + 21499904);       //  16 MB  [4][16][4096][32] bf16
  float* lpart    = (float*)(ws + 38277120);       //   1 MB  [4][16][4096]

  const float QS = 0.17677669529663687f * 1.4426950408889634f;  // scale*log2e

  prep_kernel<<<80, 256, 0, stream>>>(emb, t, ada_w, ada_b, scsh,
                                      qkv_w, qkv_wt, proj_w, proj_wt);
  ln_kernel<<<2048, 256, 0, stream>>>(x, scsh, xb);
  gemm_qkv<<<dim3(64, 12), 256, 0, stream>>>(xb, qkv_wt, qkv_b, QS, qk_out, vT);
  attn_kernel<<<2048, 256, 0, stream>>>(qk_out, vT, OpB, lpart);
  proj_kernel<<<dim3(64, 4), 256, 0, stream>>>(OpB, lpart, proj_wt, proj_b,
                                               (float*)d_out);
}